// Round 6
// baseline (316.345 us; speedup 1.0000x reference)
//
#include <hip/hip_runtime.h>
#include <cstdint>
#include <cstddef>

#define M_TOT 32768   // B*N
#define D_    256
#define DN_   128
#define TWO_D 512
#define H_    1024
#define TWO_H 2048

typedef unsigned short ushort_t;
typedef __attribute__((ext_vector_type(8))) short bf16x8;  // 8 bf16 = 4 VGPRs
typedef __attribute__((ext_vector_type(4))) float f32x4;

__device__ __forceinline__ ushort_t f2bf(float f) {
  union { float f; uint32_t i; } v; v.f = f;
  uint32_t r = v.i + 0x7fffu + ((v.i >> 16) & 1u);
  return (ushort_t)(r >> 16);
}

__device__ __forceinline__ void async_ld16(const void* g, void* l) {
  __builtin_amdgcn_global_load_lds(
      (const __attribute__((address_space(1))) void*)g,
      (__attribute__((address_space(3))) void*)l, 16, 0, 0);
}

// ---------------- fused prep: cond_ss + transpose(w_in) + transpose(w_out) + gather
// Sections by blockIdx.x: [0,16) cond, [16,144) w_in T, [144,208) w_out T, [208,336) gather.
__device__ __forceinline__ void transpose_body(
    const float* __restrict__ in, ushort_t* __restrict__ out, int R, int C,
    int bb, int tid, float* T) {
  int ctiles = C >> 6;
  int bi = bb / ctiles, bj = bb % ctiles;
  int r0 = bi * 64, c0 = bj * 64;
#pragma unroll
  for (int it = 0; it < 16; ++it) {
    int idx = it * 256 + tid;            // 0..4095
    int r = idx >> 6, c = idx & 63;
    T[r * 65 + c] = in[(size_t)(r0 + r) * C + c0 + c];
  }
  __syncthreads();
#pragma unroll
  for (int it = 0; it < 8; ++it) {
    int idx = it * 256 + tid;            // 0..2047
    int a = idx >> 5;                    // in-col -> out row
    int b = (idx & 31) * 2;              // in-row pair -> out col pair
    uint32_t pk = (uint32_t)f2bf(T[b * 65 + a]) |
                  ((uint32_t)f2bf(T[(b + 1) * 65 + a]) << 16);
    *(uint32_t*)&out[(size_t)(c0 + a) * R + r0 + b] = pk;
  }
}

__global__ __launch_bounds__(256) void prep_kernel(
    const float* __restrict__ ctx, const float* __restrict__ cond_w,
    const float* __restrict__ cond_b, float* __restrict__ ss,
    const float* __restrict__ w_in, ushort_t* __restrict__ WinT,
    const float* __restrict__ w_out, ushort_t* __restrict__ WoutT,
    const float* __restrict__ emb, const int* __restrict__ idx,
    ushort_t* __restrict__ W2T) {
  __shared__ float T[64 * 65];
  int bid = blockIdx.x, tid = threadIdx.x;
  if (bid < 16) {
    // cond_ss: ss[b][j] = ctx[b]·cond_w[:,j] + cond_b[j]
    int j = bid * 256 + tid;             // b = j>>9, col = j&511
    int b = j >> 9, col = j & 511;
    float acc = cond_b[col];
    for (int k = 0; k < DN_; ++k)
      acc += ctx[b * DN_ + k] * cond_w[k * TWO_D + col];
    ss[j] = acc;
  } else if (bid < 144) {
    transpose_body(w_in, WinT, D_, TWO_H, bid - 16, tid, T);
  } else if (bid < 208) {
    transpose_body(w_out, WoutT, H_, D_, bid - 144, tid, T);
  } else {
    // gather: W2T[f*8+o][d] = emb[idx[f]][d*8+o]
    int f = bid - 208;                   // 0..127
    bool looks64 = (idx[1] == 0) & (idx[3] == 0) & (idx[5] == 0) & (idx[7] == 0);
    int fi = looks64 ? idx[2 * f] : idx[f];
    const float* src = emb + (size_t)fi * 2048;
    int o = tid >> 5, d0 = (tid & 31) * 8;
    ushort_t buf[8];
#pragma unroll
    for (int k = 0; k < 8; ++k) buf[k] = f2bf(src[(d0 + k) * 8 + o]);
    *(bf16x8*)&W2T[(size_t)(f * 8 + o) * 256 + d0] = *(bf16x8*)buf;
  }
}

// ---------------- fused LayerNorm + FiLM  (one wave per row of 256), f32 in -> bf16 out
__global__ __launch_bounds__(256) void ln_film_kernel(
    const float* __restrict__ x, const float* __restrict__ ss,
    ushort_t* __restrict__ h) {
  int row = blockIdx.x * 4 + (threadIdx.x >> 6);
  int lane = threadIdx.x & 63;
  int b = row >> 12;
  const float* xr = x + (size_t)row * D_;
  float4 pk = *(const float4*)(xr + lane * 4);
  float f0 = pk.x, f1 = pk.y, f2 = pk.z, f3 = pk.w;
  float s = f0 + f1 + f2 + f3;
  float q = f0 * f0 + f1 * f1 + f2 * f2 + f3 * f3;
#pragma unroll
  for (int off = 32; off > 0; off >>= 1) {
    s += __shfl_xor(s, off, 64);
    q += __shfl_xor(q, off, 64);
  }
  float mean = s * (1.0f / 256.0f);
  float var = q * (1.0f / 256.0f) - mean * mean;
  float rs = rsqrtf(var + 1e-5f);
  int d = lane * 4;
  const float* ssb = ss + b * TWO_D;
  float o0 = (f0 - mean) * rs * (1.0f + ssb[d + 0]) + ssb[256 + d + 0];
  float o1 = (f1 - mean) * rs * (1.0f + ssb[d + 1]) + ssb[256 + d + 1];
  float o2 = (f2 - mean) * rs * (1.0f + ssb[d + 2]) + ssb[256 + d + 2];
  float o3 = (f3 - mean) * rs * (1.0f + ssb[d + 3]) + ssb[256 + d + 3];
  uint2 st;
  st.x = (uint32_t)f2bf(o0) | ((uint32_t)f2bf(o1) << 16);
  st.y = (uint32_t)f2bf(o2) | ((uint32_t)f2bf(o3) << 16);
  *(uint2*)(h + (size_t)row * D_ + lane * 4) = st;
}

// ---------------- fused gated-FFN: y = (gelu(h@Wu+bu)*(h@Wv+bv)) @ Wout + bout
// (round-4 structure: 128-row blocks, 512 threads, 8 waves 4x2 grid, 32-row
// reg-resident A, 2 MFMAs per B-frag read, swizzled tiles, 6-phase ring,
// counted vmcnt(2) entries — 86.5 µs, no spill)
__global__ __launch_bounds__(512, 2) void ffn_fused_kernel(
    const ushort_t* __restrict__ h,      // [32768][256] bf16
    const ushort_t* __restrict__ WinT,   // [2048][256] bf16 (u rows 0..1023, v 1024..2047)
    const float* __restrict__ bin,       // [2048] f32
    const ushort_t* __restrict__ WoutT,  // [256][1024] bf16
    const float* __restrict__ bout,      // [256] f32
    ushort_t* __restrict__ y) {          // [32768][256] bf16
  __shared__ ushort_t S3[3][8192];       // 3 x 16 KB staging ring
  __shared__ ushort_t Gs[128 * 72];      // 18.4 KB: g chunk, row-major stride 72
  __shared__ float Lbin[2048];           // 8 KB: bin biases
  const int tid = threadIdx.x, lane = tid & 63, wave = tid >> 6;  // wave 0..7
  const int wm = wave >> 1, wn = wave & 1;       // wm 0..3 row-quads
  const int r = lane >> 2, q = lane & 3;         // staging lane decomposition
  const int qs = q ^ ((r >> 1) & 3);             // swizzled source col-chunk
  const int l15 = lane & 15, l4 = lane >> 4;
  const int m0 = blockIdx.x * 128;
  // swizzled fragment offset inside a 16x32 tile (ushort units)
  const int fragoff = l15 * 32 + (l4 ^ ((l15 >> 1) & 3)) * 8;

  // per-thread staging bases (bytes)
  const char* winb  = (const char*)WinT  + r * 512 + qs * 16;
  const char* woutb = (const char*)WoutT + r * 2048 + qs * 16;

  // A fragments: this wave's 32 h-rows, all K=256, in registers (64 VGPR)
  const ushort_t* hp = h + (size_t)(m0 + wm * 32 + l15) * 256 + l4 * 8;
  bf16x8 a_reg[2][8];
#pragma unroll
  for (int rt = 0; rt < 2; ++rt)
#pragma unroll
    for (int kc = 0; kc < 8; ++kc)
      a_reg[rt][kc] = *(const bf16x8*)(hp + rt * 4096 + kc * 32);

  // bin -> LDS (one DMA per wave, pure-DMA keeps vmcnt counts exact)
  async_ld16((const char*)bin + wave * 1024 + lane * 16,
             (char*)Lbin + wave * 1024);

  auto stage_in = [&](ushort_t* dst, int jrow, int k0e) {
#pragma unroll
    for (int i = 0; i < 2; ++i) {
      int tt = i * 8 + wave;             // 0..15; <8 = u, >=8 = v
      int vv = tt >> 3, t7 = tt & 7;
      int ks = t7 >> 2, cc = t7 & 3;     // K-32 sub, gate-col-16 group
      async_ld16(winb + (size_t)vv * 524288 + jrow * 32768 + cc * 8192 +
                     k0e * 2 + ks * 64,
                 &dst[tt * 512]);
    }
  };
  auto stage_wout = [&](ushort_t* dst, int jrow, int s2) {
#pragma unroll
    for (int i = 0; i < 2; ++i) {
      int tt = i * 8 + wave;             // out-col tile nt
      async_ld16(woutb + (size_t)tt * 32768 + jrow * 128 + s2 * 64,
                 &dst[tt * 512]);
    }
  };

  // prologue: first two in-proj quarters of chunk 0
  stage_in(S3[0], 0, 0);
  stage_in(S3[1], 0, 64);

  f32x4 yac[2][8] = {};                  // rows rt*16, out-cols wn*128 + nt8*16

#define ENTRY2()                                        \
  asm volatile("s_waitcnt vmcnt(2)" ::: "memory");      \
  __builtin_amdgcn_s_barrier();                         \
  asm volatile("" ::: "memory");
#define ENTRY2L()                                                  \
  asm volatile("s_waitcnt vmcnt(2) lgkmcnt(0)" ::: "memory");      \
  __builtin_amdgcn_s_barrier();                                    \
  asm volatile("" ::: "memory");

#define MFMA_IN(buf, p_)                                                      \
  {                                                                           \
    const ushort_t* cur_ = (buf);                                             \
    __builtin_amdgcn_s_setprio(1);                                            \
    _Pragma("unroll")                                                         \
    for (int ks = 0; ks < 2; ++ks) {                                          \
      _Pragma("unroll")                                                       \
      for (int jj = 0; jj < 2; ++jj) {                                        \
        int tt = ks * 4 + wn * 2 + jj;                                        \
        bf16x8 bu = *(const bf16x8*)&cur_[tt * 512 + fragoff];                \
        bf16x8 bv = *(const bf16x8*)&cur_[(8 + tt) * 512 + fragoff];          \
        uac[0][jj] = __builtin_amdgcn_mfma_f32_16x16x32_bf16(a_reg[0][(p_)*2+ks], bu, uac[0][jj], 0, 0, 0); \
        uac[1][jj] = __builtin_amdgcn_mfma_f32_16x16x32_bf16(a_reg[1][(p_)*2+ks], bu, uac[1][jj], 0, 0, 0); \
        vac[0][jj] = __builtin_amdgcn_mfma_f32_16x16x32_bf16(a_reg[0][(p_)*2+ks], bv, vac[0][jj], 0, 0, 0); \
        vac[1][jj] = __builtin_amdgcn_mfma_f32_16x16x32_bf16(a_reg[1][(p_)*2+ks], bv, vac[1][jj], 0, 0, 0); \
      }                                                                       \
    }                                                                         \
    __builtin_amdgcn_s_setprio(0);                                            \
  }

#define MFMA_OUT(buf, s2_)                                                    \
  {                                                                           \
    const ushort_t* cur_ = (buf);                                             \
    bf16x8 gf0 = *(const bf16x8*)&Gs[(wm * 32 + l15) * 72 + (s2_) * 32 + l4 * 8];      \
    bf16x8 gf1 = *(const bf16x8*)&Gs[(wm * 32 + 16 + l15) * 72 + (s2_) * 32 + l4 * 8]; \
    __builtin_amdgcn_s_setprio(1);                                            \
    _Pragma("unroll")                                                         \
    for (int nt8 = 0; nt8 < 8; ++nt8) {                                       \
      bf16x8 bw = *(const bf16x8*)&cur_[(wn * 8 + nt8) * 512 + fragoff];      \
      yac[0][nt8] = __builtin_amdgcn_mfma_f32_16x16x32_bf16(gf0, bw, yac[0][nt8], 0, 0, 0); \
      yac[1][nt8] = __builtin_amdgcn_mfma_f32_16x16x32_bf16(gf1, bw, yac[1][nt8], 0, 0, 0); \
    }                                                                         \
    __builtin_amdgcn_s_setprio(0);                                            \
  }

  for (int j = 0; j < 16; ++j) {
    const int jn = (j + 1) & 15;         // wrap keeps vmcnt counts uniform
    f32x4 uac[2][2] = {}, vac[2][2] = {};

    ENTRY2(); stage_in(S3[2], j, 128);  MFMA_IN(S3[0], 0);   // p0
    ENTRY2(); stage_in(S3[0], j, 192);  MFMA_IN(S3[1], 1);   // p1
    ENTRY2(); stage_wout(S3[1], j, 0);  MFMA_IN(S3[2], 2);   // p2
    ENTRY2(); stage_wout(S3[2], j, 1);  MFMA_IN(S3[0], 3);   // p3

    // gelu-gate -> Gs (this wave's 32 rows x 32 gate-cols); flushed at p4 entry
#pragma unroll
    for (int jj = 0; jj < 2; ++jj) {
      int gcol = wn * 32 + jj * 16 + l15;
      float bub = Lbin[j * 64 + gcol];
      float bvb = Lbin[1024 + j * 64 + gcol];
#pragma unroll
      for (int rt = 0; rt < 2; ++rt) {
#pragma unroll
        for (int rr = 0; rr < 4; ++rr) {
          float u = uac[rt][jj][rr] + bub;
          float v = vac[rt][jj][rr] + bvb;
          float t = 0.7978845608028654f * (u + 0.044715f * u * u * u);
          float e = __expf(2.0f * t);
          float th = 1.0f - 2.0f / (e + 1.0f);
          float gl = 0.5f * u * (1.0f + th);
          Gs[(wm * 32 + rt * 16 + l4 * 4 + rr) * 72 + gcol] = f2bf(gl * v);
        }
      }
    }

    ENTRY2L(); stage_in(S3[0], jn, 0);  MFMA_OUT(S3[1], 0);  // p4
    ENTRY2();  stage_in(S3[1], jn, 64); MFMA_OUT(S3[2], 1);  // p5
  }

  // epilogue: y + bout -> bf16 via E (stride 264), two 64-row halves
  asm volatile("s_waitcnt vmcnt(0)" ::: "memory");
  __builtin_amdgcn_s_barrier();
  asm volatile("" ::: "memory");
  ushort_t* E = &S3[0][0];               // 64 x 264 x 2B = 33.8 KB (spans ring)
#pragma unroll
  for (int hh = 0; hh < 2; ++hh) {
    if ((wm >> 1) == hh) {
      int er0 = (wm & 1) * 32;
#pragma unroll
      for (int nt8 = 0; nt8 < 8; ++nt8) {
        int col = wn * 128 + nt8 * 16 + l15;
        float bb = bout[col];
#pragma unroll
        for (int rt = 0; rt < 2; ++rt)
#pragma unroll
          for (int rr = 0; rr < 4; ++rr)
            E[(er0 + rt * 16 + l4 * 4 + rr) * 264 + col] = f2bf(yac[rt][nt8][rr] + bb);
      }
    }
    asm volatile("s_waitcnt lgkmcnt(0)" ::: "memory");
    __builtin_amdgcn_s_barrier();
    asm volatile("" ::: "memory");
#pragma unroll
    for (int it = 0; it < 4; ++it) {
      int id = it * 512 + tid;           // 0..2047: rr = row, cc = 8-col chunk
      int rr = id >> 5, cc = id & 31;
      bf16x8 vv = *(const bf16x8*)&E[rr * 264 + cc * 8];
      *(bf16x8*)&y[(size_t)(m0 + hh * 64 + rr) * 256 + cc * 8] = vv;
    }
    if (hh == 0) {
      __builtin_amdgcn_s_barrier();      // readers done before E is rewritten
      asm volatile("" ::: "memory");
    }
  }
#undef ENTRY2
#undef ENTRY2L
#undef MFMA_IN
#undef MFMA_OUT
}

// ---------------- out GEMM: out[M][1024] = y[M][256] @ W2T[1024][256]^T, f32 out
// Reg-direct (no staging LDS, no main-loop barriers): A is L3-resident (just
// written by ffn), B (0.5 MB) is L2-resident. Block = 64 rows x 256 cols,
// 4 waves side-by-side in N; VGPR-capped 128 -> 4 blocks/CU (4 waves/SIMD,
// 2x the TLP of the staged version) for latency hiding. K fully unrolled.
// Coalesced Cs-roundtrip epilogue (33 KB, fits 4 blocks/CU).
__global__ __launch_bounds__(256, 4) void gemm_out_kernel(
    const ushort_t* __restrict__ A, const ushort_t* __restrict__ BT,
    float* __restrict__ C) {
  __shared__ float Cs[32 * 260];         // 33.3 KB epilogue staging
  const int tid = threadIdx.x, lane = tid & 63, wave = tid >> 6;  // wave = n-quarter
  const int l15 = lane & 15, l4 = lane >> 4;
  const int m0 = blockIdx.y * 64;        // grid (4, 512): consecutive blocks share A panel
  const int n0 = blockIdx.x * 256;
  const ushort_t* Ap = A + (size_t)(m0 + l15) * 256 + l4 * 8;
  const ushort_t* Bp = BT + (size_t)(n0 + wave * 64 + l15) * 256 + l4 * 8;
  f32x4 acc[4][4] = {};
#pragma unroll
  for (int k0 = 0; k0 < 256; k0 += 64) {
#pragma unroll
    for (int ks = 0; ks < 2; ++ks) {
      bf16x8 a[4], b[4];
#pragma unroll
      for (int i = 0; i < 4; ++i)
        a[i] = *(const bf16x8*)(Ap + i * 4096 + k0 + ks * 32);
#pragma unroll
      for (int jt = 0; jt < 4; ++jt)
        b[jt] = *(const bf16x8*)(Bp + jt * 4096 + k0 + ks * 32);
#pragma unroll
      for (int i = 0; i < 4; ++i)
#pragma unroll
        for (int jt = 0; jt < 4; ++jt)
          acc[i][jt] = __builtin_amdgcn_mfma_f32_16x16x32_bf16(a[i], b[jt], acc[i][jt], 0, 0, 0);
    }
  }
  // epilogue: two 32-row passes through Cs, fully-coalesced 1KB-row stores
#pragma unroll
  for (int p = 0; p < 2; ++p) {
    __syncthreads();
#pragma unroll
    for (int ii = 0; ii < 2; ++ii) {
      int i = p * 2 + ii;
#pragma unroll
      for (int jt = 0; jt < 4; ++jt)
#pragma unroll
        for (int rr = 0; rr < 4; ++rr)
          Cs[(ii * 16 + l4 * 4 + rr) * 260 + wave * 64 + jt * 16 + l15] = acc[i][jt][rr];
    }
    __syncthreads();
#pragma unroll
    for (int it = 0; it < 8; ++it) {
      int id = it * 256 + tid;           // 0..2047
      int rr = id >> 6, c = (id & 63) * 4;  // 32 rows x 256 cols
      float4 v = *(const float4*)&Cs[rr * 260 + c];
      *(float4*)&C[(size_t)(m0 + p * 32 + rr) * 1024 + n0 + c] = v;
    }
  }
}

extern "C" void kernel_launch(void* const* d_in, const int* in_sizes, int n_in,
                              void* d_out, int out_size, void* d_ws, size_t ws_size,
                              hipStream_t stream) {
  const float* x      = (const float*)d_in[0];
  const float* ctx    = (const float*)d_in[1];
  const int*   idx    = (const int*)d_in[2];
  const float* cond_w = (const float*)d_in[3];
  const float* cond_b = (const float*)d_in[4];
  const float* w_in   = (const float*)d_in[5];
  const float* b_in   = (const float*)d_in[6];
  const float* w_out  = (const float*)d_in[7];
  const float* b_out  = (const float*)d_in[8];
  const float* emb    = (const float*)d_in[9];

  char* w = (char*)d_ws;
  float* ss = (float*)w;           w += (size_t)8 * TWO_D * 4;        // 16 KB
  ushort_t* h = (ushort_t*)w;      w += (size_t)M_TOT * D_ * 2;       // 16.8 MB
  ushort_t* y = (ushort_t*)w;      w += (size_t)M_TOT * D_ * 2;       // 16.8 MB
  ushort_t* WinT = (ushort_t*)w;   w += (size_t)TWO_H * D_ * 2;       // 1 MB
  ushort_t* WoutT = (ushort_t*)w;  w += (size_t)D_ * H_ * 2;          // 0.5 MB
  ushort_t* W2T = (ushort_t*)w;    w += (size_t)H_ * D_ * 2;          // 0.5 MB

  prep_kernel<<<336, 256, 0, stream>>>(ctx, cond_w, cond_b, ss,
                                       w_in, WinT, w_out, WoutT, emb, idx, W2T);
  ln_film_kernel<<<M_TOT / 4, 256, 0, stream>>>(x, ss, h);
  ffn_fused_kernel<<<M_TOT / 128, 512, 0, stream>>>(h, WinT, b_in, WoutT, b_out, y);
  gemm_out_kernel<<<dim3(4, 512), 256, 0, stream>>>(y, W2T, (float*)d_out);
}

// Round 7
// 297.794 us; speedup vs baseline: 1.0623x; 1.0623x over previous
//
#include <hip/hip_runtime.h>
#include <cstdint>
#include <cstddef>

#define M_TOT 32768   // B*N
#define D_    256
#define DN_   128
#define TWO_D 512
#define H_    1024
#define TWO_H 2048

typedef unsigned short ushort_t;
typedef __attribute__((ext_vector_type(8))) short bf16x8;  // 8 bf16 = 4 VGPRs
typedef __attribute__((ext_vector_type(4))) float f32x4;

__device__ __forceinline__ ushort_t f2bf(float f) {
  union { float f; uint32_t i; } v; v.f = f;
  uint32_t r = v.i + 0x7fffu + ((v.i >> 16) & 1u);
  return (ushort_t)(r >> 16);
}

__device__ __forceinline__ void async_ld16(const void* g, void* l) {
  __builtin_amdgcn_global_load_lds(
      (const __attribute__((address_space(1))) void*)g,
      (__attribute__((address_space(3))) void*)l, 16, 0, 0);
}

// ---------------- fused prep: cond_ss + transpose(w_in) + transpose(w_out) + gather
// Sections by blockIdx.x: [0,16) cond, [16,144) w_in T, [144,208) w_out T, [208,336) gather.
__device__ __forceinline__ void transpose_body(
    const float* __restrict__ in, ushort_t* __restrict__ out, int R, int C,
    int bb, int tid, float* T) {
  int ctiles = C >> 6;
  int bi = bb / ctiles, bj = bb % ctiles;
  int r0 = bi * 64, c0 = bj * 64;
#pragma unroll
  for (int it = 0; it < 16; ++it) {
    int idx = it * 256 + tid;            // 0..4095
    int r = idx >> 6, c = idx & 63;
    T[r * 65 + c] = in[(size_t)(r0 + r) * C + c0 + c];
  }
  __syncthreads();
#pragma unroll
  for (int it = 0; it < 8; ++it) {
    int idx = it * 256 + tid;            // 0..2047
    int a = idx >> 5;                    // in-col -> out row
    int b = (idx & 31) * 2;              // in-row pair -> out col pair
    uint32_t pk = (uint32_t)f2bf(T[b * 65 + a]) |
                  ((uint32_t)f2bf(T[(b + 1) * 65 + a]) << 16);
    *(uint32_t*)&out[(size_t)(c0 + a) * R + r0 + b] = pk;
  }
}

__global__ __launch_bounds__(256) void prep_kernel(
    const float* __restrict__ ctx, const float* __restrict__ cond_w,
    const float* __restrict__ cond_b, float* __restrict__ ss,
    const float* __restrict__ w_in, ushort_t* __restrict__ WinT,
    const float* __restrict__ w_out, ushort_t* __restrict__ WoutT,
    const float* __restrict__ emb, const int* __restrict__ idx,
    ushort_t* __restrict__ W2T) {
  __shared__ float T[64 * 65];
  int bid = blockIdx.x, tid = threadIdx.x;
  if (bid < 16) {
    // cond_ss: ss[b][j] = ctx[b]·cond_w[:,j] + cond_b[j]
    int j = bid * 256 + tid;             // b = j>>9, col = j&511
    int b = j >> 9, col = j & 511;
    float acc = cond_b[col];
    for (int k = 0; k < DN_; ++k)
      acc += ctx[b * DN_ + k] * cond_w[k * TWO_D + col];
    ss[j] = acc;
  } else if (bid < 144) {
    transpose_body(w_in, WinT, D_, TWO_H, bid - 16, tid, T);
  } else if (bid < 208) {
    transpose_body(w_out, WoutT, H_, D_, bid - 144, tid, T);
  } else {
    // gather: W2T[f*8+o][d] = emb[idx[f]][d*8+o]
    int f = bid - 208;                   // 0..127
    bool looks64 = (idx[1] == 0) & (idx[3] == 0) & (idx[5] == 0) & (idx[7] == 0);
    int fi = looks64 ? idx[2 * f] : idx[f];
    const float* src = emb + (size_t)fi * 2048;
    int o = tid >> 5, d0 = (tid & 31) * 8;
    ushort_t buf[8];
#pragma unroll
    for (int k = 0; k < 8; ++k) buf[k] = f2bf(src[(d0 + k) * 8 + o]);
    *(bf16x8*)&W2T[(size_t)(f * 8 + o) * 256 + d0] = *(bf16x8*)buf;
  }
}

// ---------------- fused LN+FiLM+gated-FFN: a = LNFiLM(x) in-register (h never
// materialized); y = (gelu(a@Wu+bu)*(a@Wv+bv)) @ Wout + bout.
// LN reduction replicates ln_film's butterfly tree bit-exactly: partials are
// sequential 4-elem sums; combined over element-index bits 5..0 =
// (kc^4, kc^2, kc^1 in-register; shfl_xor 32; shfl_xor 16; e-pair in-register).
// Main loop = proven R4 structure: 128-row blocks, 512 threads, 8 waves 4x2,
// 32-row reg-resident A, 2 MFMAs per B-frag read, swizzled tiles, 6-phase
// triple-buffer ring, counted vmcnt(2) entries.
__global__ __launch_bounds__(512, 2) void ffn_fused_kernel(
    const float* __restrict__ x,         // [32768][256] f32
    const float* __restrict__ ss,        // [8][512] f32 (scale | shift)
    const ushort_t* __restrict__ WinT,   // [2048][256] bf16 (u rows 0..1023, v 1024..2047)
    const float* __restrict__ bin,       // [2048] f32
    const ushort_t* __restrict__ WoutT,  // [256][1024] bf16
    const float* __restrict__ bout,      // [256] f32
    ushort_t* __restrict__ y) {          // [32768][256] bf16
  __shared__ ushort_t S3[3][8192];       // 3 x 16 KB staging ring
  __shared__ ushort_t Gs[128 * 72];      // 18.4 KB: g chunk, row-major stride 72
  __shared__ float Lbin[2048];           // 8 KB: bin biases
  const int tid = threadIdx.x, lane = tid & 63, wave = tid >> 6;  // wave 0..7
  const int wm = wave >> 1, wn = wave & 1;       // wm 0..3 row-quads
  const int r = lane >> 2, q = lane & 3;         // staging lane decomposition
  const int qs = q ^ ((r >> 1) & 3);             // swizzled source col-chunk
  const int l15 = lane & 15, l4 = lane >> 4;
  const int m0 = blockIdx.x * 128;
  // swizzled fragment offset inside a 16x32 tile (ushort units)
  const int fragoff = l15 * 32 + (l4 ^ ((l15 >> 1) & 3)) * 8;

  // per-thread staging bases (bytes)
  const char* winb  = (const char*)WinT  + r * 512 + qs * 16;
  const char* woutb = (const char*)WoutT + r * 2048 + qs * 16;

  // ---- fused LayerNorm + FiLM -> a_reg (this wave's 32 rows, all K=256)
  const float* xb = x + (size_t)(m0 + wm * 32 + l15) * 256 + l4 * 8;
  const float* ssb = ss + (m0 >> 12) * TWO_D + l4 * 8;
  bf16x8 a_reg[2][8];
#pragma unroll
  for (int rt = 0; rt < 2; ++rt) {
    const float* xr = xb + rt * 16 * 256;
    float p[8][2], qq[8][2];
#pragma unroll
    for (int kc = 0; kc < 8; ++kc) {
      float4 u0 = *(const float4*)(xr + kc * 32);
      float4 u1 = *(const float4*)(xr + kc * 32 + 4);
      p[kc][0]  = ((u0.x + u0.y) + u0.z) + u0.w;
      qq[kc][0] = ((u0.x * u0.x + u0.y * u0.y) + u0.z * u0.z) + u0.w * u0.w;
      p[kc][1]  = ((u1.x + u1.y) + u1.z) + u1.w;
      qq[kc][1] = ((u1.x * u1.x + u1.y * u1.y) + u1.z * u1.z) + u1.w * u1.w;
    }
    // tree over L bits 5,4,3 (kc, in-register)
    float s2[2], q2[2];
#pragma unroll
    for (int e = 0; e < 2; ++e) {
      float a0 = p[0][e] + p[4][e], a1 = p[1][e] + p[5][e];
      float a2 = p[2][e] + p[6][e], a3 = p[3][e] + p[7][e];
      float b0 = a0 + a2, b1 = a1 + a3;
      s2[e] = b0 + b1;
      float c0 = qq[0][e] + qq[4][e], c1 = qq[1][e] + qq[5][e];
      float c2 = qq[2][e] + qq[6][e], c3 = qq[3][e] + qq[7][e];
      float d0 = c0 + c2, d1 = c1 + c3;
      q2[e] = d0 + d1;
    }
    // bits 2,1 (lane xor 32, then 16), then bit 0 (e-pair) — ln_film order
#pragma unroll
    for (int e = 0; e < 2; ++e) {
      s2[e] += __shfl_xor(s2[e], 32, 64);
      q2[e] += __shfl_xor(q2[e], 32, 64);
      s2[e] += __shfl_xor(s2[e], 16, 64);
      q2[e] += __shfl_xor(q2[e], 16, 64);
    }
    float s = s2[0] + s2[1];
    float qsum = q2[0] + q2[1];
    float mean = s * (1.0f / 256.0f);
    float var = qsum * (1.0f / 256.0f) - mean * mean;
    float rs = rsqrtf(var + 1e-5f);
    // pass 2: reload (L2-hot), FiLM, pack bf16
#pragma unroll
    for (int kc = 0; kc < 8; ++kc) {
      float4 u0 = *(const float4*)(xr + kc * 32);
      float4 u1 = *(const float4*)(xr + kc * 32 + 4);
      float4 g0 = *(const float4*)(ssb + kc * 32);
      float4 g1 = *(const float4*)(ssb + kc * 32 + 4);
      float4 t0 = *(const float4*)(ssb + 256 + kc * 32);
      float4 t1 = *(const float4*)(ssb + 256 + kc * 32 + 4);
      ushort_t hb[8];
      hb[0] = f2bf((u0.x - mean) * rs * (1.0f + g0.x) + t0.x);
      hb[1] = f2bf((u0.y - mean) * rs * (1.0f + g0.y) + t0.y);
      hb[2] = f2bf((u0.z - mean) * rs * (1.0f + g0.z) + t0.z);
      hb[3] = f2bf((u0.w - mean) * rs * (1.0f + g0.w) + t0.w);
      hb[4] = f2bf((u1.x - mean) * rs * (1.0f + g1.x) + t1.x);
      hb[5] = f2bf((u1.y - mean) * rs * (1.0f + g1.y) + t1.y);
      hb[6] = f2bf((u1.z - mean) * rs * (1.0f + g1.z) + t1.z);
      hb[7] = f2bf((u1.w - mean) * rs * (1.0f + g1.w) + t1.w);
      a_reg[rt][kc] = *(bf16x8*)hb;
    }
  }

  // bin -> LDS (one DMA per wave, pure-DMA keeps vmcnt counts exact)
  async_ld16((const char*)bin + wave * 1024 + lane * 16,
             (char*)Lbin + wave * 1024);

  auto stage_in = [&](ushort_t* dst, int jrow, int k0e) {
#pragma unroll
    for (int i = 0; i < 2; ++i) {
      int tt = i * 8 + wave;             // 0..15; <8 = u, >=8 = v
      int vv = tt >> 3, t7 = tt & 7;
      int ks = t7 >> 2, cc = t7 & 3;     // K-32 sub, gate-col-16 group
      async_ld16(winb + (size_t)vv * 524288 + jrow * 32768 + cc * 8192 +
                     k0e * 2 + ks * 64,
                 &dst[tt * 512]);
    }
  };
  auto stage_wout = [&](ushort_t* dst, int jrow, int s2) {
#pragma unroll
    for (int i = 0; i < 2; ++i) {
      int tt = i * 8 + wave;             // out-col tile nt
      async_ld16(woutb + (size_t)tt * 32768 + jrow * 128 + s2 * 64,
                 &dst[tt * 512]);
    }
  };

  // prologue: first two in-proj quarters of chunk 0
  stage_in(S3[0], 0, 0);
  stage_in(S3[1], 0, 64);

  f32x4 yac[2][8] = {};                  // rows rt*16, out-cols wn*128 + nt8*16

#define ENTRY2()                                        \
  asm volatile("s_waitcnt vmcnt(2)" ::: "memory");      \
  __builtin_amdgcn_s_barrier();                         \
  asm volatile("" ::: "memory");
#define ENTRY2L()                                                  \
  asm volatile("s_waitcnt vmcnt(2) lgkmcnt(0)" ::: "memory");      \
  __builtin_amdgcn_s_barrier();                                    \
  asm volatile("" ::: "memory");

#define MFMA_IN(buf, p_)                                                      \
  {                                                                           \
    const ushort_t* cur_ = (buf);                                             \
    __builtin_amdgcn_s_setprio(1);                                            \
    _Pragma("unroll")                                                         \
    for (int ks = 0; ks < 2; ++ks) {                                          \
      _Pragma("unroll")                                                       \
      for (int jj = 0; jj < 2; ++jj) {                                        \
        int tt = ks * 4 + wn * 2 + jj;                                        \
        bf16x8 bu = *(const bf16x8*)&cur_[tt * 512 + fragoff];                \
        bf16x8 bv = *(const bf16x8*)&cur_[(8 + tt) * 512 + fragoff];          \
        uac[0][jj] = __builtin_amdgcn_mfma_f32_16x16x32_bf16(a_reg[0][(p_)*2+ks], bu, uac[0][jj], 0, 0, 0); \
        uac[1][jj] = __builtin_amdgcn_mfma_f32_16x16x32_bf16(a_reg[1][(p_)*2+ks], bu, uac[1][jj], 0, 0, 0); \
        vac[0][jj] = __builtin_amdgcn_mfma_f32_16x16x32_bf16(a_reg[0][(p_)*2+ks], bv, vac[0][jj], 0, 0, 0); \
        vac[1][jj] = __builtin_amdgcn_mfma_f32_16x16x32_bf16(a_reg[1][(p_)*2+ks], bv, vac[1][jj], 0, 0, 0); \
      }                                                                       \
    }                                                                         \
    __builtin_amdgcn_s_setprio(0);                                            \
  }

#define MFMA_OUT(buf, s2_)                                                    \
  {                                                                           \
    const ushort_t* cur_ = (buf);                                             \
    bf16x8 gf0 = *(const bf16x8*)&Gs[(wm * 32 + l15) * 72 + (s2_) * 32 + l4 * 8];      \
    bf16x8 gf1 = *(const bf16x8*)&Gs[(wm * 32 + 16 + l15) * 72 + (s2_) * 32 + l4 * 8]; \
    __builtin_amdgcn_s_setprio(1);                                            \
    _Pragma("unroll")                                                         \
    for (int nt8 = 0; nt8 < 8; ++nt8) {                                       \
      bf16x8 bw = *(const bf16x8*)&cur_[(wn * 8 + nt8) * 512 + fragoff];      \
      yac[0][nt8] = __builtin_amdgcn_mfma_f32_16x16x32_bf16(gf0, bw, yac[0][nt8], 0, 0, 0); \
      yac[1][nt8] = __builtin_amdgcn_mfma_f32_16x16x32_bf16(gf1, bw, yac[1][nt8], 0, 0, 0); \
    }                                                                         \
    __builtin_amdgcn_s_setprio(0);                                            \
  }

  for (int j = 0; j < 16; ++j) {
    const int jn = (j + 1) & 15;         // wrap keeps vmcnt counts uniform
    f32x4 uac[2][2] = {}, vac[2][2] = {};

    ENTRY2(); stage_in(S3[2], j, 128);  MFMA_IN(S3[0], 0);   // p0
    ENTRY2(); stage_in(S3[0], j, 192);  MFMA_IN(S3[1], 1);   // p1
    ENTRY2(); stage_wout(S3[1], j, 0);  MFMA_IN(S3[2], 2);   // p2
    ENTRY2(); stage_wout(S3[2], j, 1);  MFMA_IN(S3[0], 3);   // p3

    // gelu-gate -> Gs (this wave's 32 rows x 32 gate-cols); flushed at p4 entry
#pragma unroll
    for (int jj = 0; jj < 2; ++jj) {
      int gcol = wn * 32 + jj * 16 + l15;
      float bub = Lbin[j * 64 + gcol];
      float bvb = Lbin[1024 + j * 64 + gcol];
#pragma unroll
      for (int rt = 0; rt < 2; ++rt) {
#pragma unroll
        for (int rr = 0; rr < 4; ++rr) {
          float u = uac[rt][jj][rr] + bub;
          float v = vac[rt][jj][rr] + bvb;
          float t = 0.7978845608028654f * (u + 0.044715f * u * u * u);
          float e = __expf(2.0f * t);
          float th = 1.0f - 2.0f / (e + 1.0f);
          float gl = 0.5f * u * (1.0f + th);
          Gs[(wm * 32 + rt * 16 + l4 * 4 + rr) * 72 + gcol] = f2bf(gl * v);
        }
      }
    }

    ENTRY2L(); stage_in(S3[0], jn, 0);  MFMA_OUT(S3[1], 0);  // p4
    ENTRY2();  stage_in(S3[1], jn, 64); MFMA_OUT(S3[2], 1);  // p5
  }

  // epilogue: y + bout -> bf16 via E (stride 264), two 64-row halves
  asm volatile("s_waitcnt vmcnt(0)" ::: "memory");
  __builtin_amdgcn_s_barrier();
  asm volatile("" ::: "memory");
  ushort_t* E = &S3[0][0];               // 64 x 264 x 2B = 33.8 KB (spans ring)
#pragma unroll
  for (int hh = 0; hh < 2; ++hh) {
    if ((wm >> 1) == hh) {
      int er0 = (wm & 1) * 32;
#pragma unroll
      for (int nt8 = 0; nt8 < 8; ++nt8) {
        int col = wn * 128 + nt8 * 16 + l15;
        float bb = bout[col];
#pragma unroll
        for (int rt = 0; rt < 2; ++rt)
#pragma unroll
          for (int rr = 0; rr < 4; ++rr)
            E[(er0 + rt * 16 + l4 * 4 + rr) * 264 + col] = f2bf(yac[rt][nt8][rr] + bb);
      }
    }
    asm volatile("s_waitcnt lgkmcnt(0)" ::: "memory");
    __builtin_amdgcn_s_barrier();
    asm volatile("" ::: "memory");
#pragma unroll
    for (int it = 0; it < 4; ++it) {
      int id = it * 512 + tid;           // 0..2047: rr = row, cc = 8-col chunk
      int rr = id >> 5, cc = id & 31;
      bf16x8 vv = *(const bf16x8*)&E[rr * 264 + cc * 8];
      *(bf16x8*)&y[(size_t)(m0 + hh * 64 + rr) * 256 + cc * 8] = vv;
    }
    if (hh == 0) {
      __builtin_amdgcn_s_barrier();      // readers done before E is rewritten
      asm volatile("" ::: "memory");
    }
  }
#undef ENTRY2
#undef ENTRY2L
#undef MFMA_IN
#undef MFMA_OUT
}

// ---------------- out GEMM: out[M][1024] = y[M][256] @ W2T[1024][256]^T, f32 out
// 128x128 tile, BK=64, ping-pong 2x32KB staging with counted vmcnt(8),
// swizzled tiles, Cs-roundtrip coalesced float4 epilogue (Cs aliases SB).
__global__ __launch_bounds__(256, 2) void gemm_out_kernel(
    const ushort_t* __restrict__ A, const ushort_t* __restrict__ BT,
    float* __restrict__ C) {
  __shared__ ushort_t SB[2][16384];      // per buf: A tiles 0..15, B tiles 16..31
  const int tid = threadIdx.x, lane = tid & 63, wave = tid >> 6;
  const int wm = wave >> 1, wn = wave & 1;
  const int m0 = blockIdx.x * 128, n0 = blockIdx.y * 128;
  const int r = lane >> 2, q = lane & 3;
  const int qs = q ^ ((r >> 1) & 3);     // swizzled source col-chunk
  const int l15 = lane & 15, l4 = lane >> 4;
  const int fragoff = l15 * 32 + (l4 ^ ((l15 >> 1) & 3)) * 8;
  const int N = 1024, K = 256;

  auto stage = [&](ushort_t* dst, int k0) {
#pragma unroll
    for (int i = 0; i < 4; ++i) {
      int t = i * 4 + wave;              // 0..15
      int rt = t >> 1, ks = t & 1;
      async_ld16(A + (size_t)(m0 + rt * 16 + r) * K + k0 + ks * 32 + qs * 8, &dst[t * 512]);
      async_ld16(BT + (size_t)(n0 + rt * 16 + r) * K + k0 + ks * 32 + qs * 8, &dst[(16 + t) * 512]);
    }
  };

  f32x4 acc[4][4] = {};
  stage(SB[0], 0);                       // 8 DMA/wave
#pragma unroll
  for (int ki = 0; ki < 4; ++ki) {
    __builtin_amdgcn_s_barrier();        // prev buffer's readers done
    asm volatile("" ::: "memory");
    if (ki < 3) {
      stage(SB[(ki + 1) & 1], (ki + 1) * 64);
      asm volatile("s_waitcnt vmcnt(8)" ::: "memory");   // cur landed, next in flight
    } else {
      asm volatile("s_waitcnt vmcnt(0)" ::: "memory");   // last group (issued 1 iter ago)
    }
    __builtin_amdgcn_s_barrier();
    asm volatile("" ::: "memory");
    const ushort_t* cur = SB[ki & 1];
    __builtin_amdgcn_s_setprio(1);
#pragma unroll
    for (int ks = 0; ks < 2; ++ks) {
      bf16x8 a[4], b[4];
#pragma unroll
      for (int i = 0; i < 4; ++i)
        a[i] = *(const bf16x8*)&cur[((wm * 4 + i) * 2 + ks) * 512 + fragoff];
#pragma unroll
      for (int jt = 0; jt < 4; ++jt)
        b[jt] = *(const bf16x8*)&cur[(16 + (wn * 4 + jt) * 2 + ks) * 512 + fragoff];
#pragma unroll
      for (int i = 0; i < 4; ++i)
#pragma unroll
        for (int jt = 0; jt < 4; ++jt)
          acc[i][jt] = __builtin_amdgcn_mfma_f32_16x16x32_bf16(a[i], b[jt], acc[i][jt], 0, 0, 0);
    }
    __builtin_amdgcn_s_setprio(0);
  }
  // coalesced epilogue via Cs (aliases SB; all staging drained above)
  float* Cs = (float*)&SB[0][0];         // 64 x 132 f32 = 33.8 KB
#pragma unroll
  for (int p = 0; p < 2; ++p) {
    __builtin_amdgcn_s_barrier();
    asm volatile("" ::: "memory");
    if (wm == p) {
#pragma unroll
      for (int jt = 0; jt < 4; ++jt) {
        int col = wn * 64 + jt * 16 + l15;
#pragma unroll
        for (int i = 0; i < 4; ++i) {
          int rl = i * 16 + (l4 << 2);
#pragma unroll
          for (int rr = 0; rr < 4; ++rr)
            Cs[(rl + rr) * 132 + col] = acc[i][jt][rr];
        }
      }
    }
    asm volatile("s_waitcnt lgkmcnt(0)" ::: "memory");
    __builtin_amdgcn_s_barrier();
    asm volatile("" ::: "memory");
#pragma unroll
    for (int it = 0; it < 8; ++it) {
      int t = it * 256 + tid;            // 0..2047
      int rr = t >> 5, c = (t & 31) * 4; // row 0..63, col 0..124
      float4 v = *(const float4*)&Cs[rr * 132 + c];
      *(float4*)&C[(size_t)(m0 + p * 64 + rr) * N + n0 + c] = v;
    }
  }
}

extern "C" void kernel_launch(void* const* d_in, const int* in_sizes, int n_in,
                              void* d_out, int out_size, void* d_ws, size_t ws_size,
                              hipStream_t stream) {
  const float* x      = (const float*)d_in[0];
  const float* ctx    = (const float*)d_in[1];
  const int*   idx    = (const int*)d_in[2];
  const float* cond_w = (const float*)d_in[3];
  const float* cond_b = (const float*)d_in[4];
  const float* w_in   = (const float*)d_in[5];
  const float* b_in   = (const float*)d_in[6];
  const float* w_out  = (const float*)d_in[7];
  const float* b_out  = (const float*)d_in[8];
  const float* emb    = (const float*)d_in[9];

  char* w = (char*)d_ws;
  float* ss = (float*)w;           w += (size_t)8 * TWO_D * 4;        // 16 KB
  ushort_t* y = (ushort_t*)w;      w += (size_t)M_TOT * D_ * 2;       // 16.8 MB
  ushort_t* WinT = (ushort_t*)w;   w += (size_t)TWO_H * D_ * 2;       // 1 MB
  ushort_t* WoutT = (ushort_t*)w;  w += (size_t)D_ * H_ * 2;          // 0.5 MB
  ushort_t* W2T = (ushort_t*)w;    w += (size_t)H_ * D_ * 2;          // 0.5 MB

  prep_kernel<<<336, 256, 0, stream>>>(ctx, cond_w, cond_b, ss,
                                       w_in, WinT, w_out, WoutT, emb, idx, W2T);
  ffn_fused_kernel<<<M_TOT / 128, 512, 0, stream>>>(x, ss, WinT, b_in, WoutT, b_out, y);
  gemm_out_kernel<<<dim3(M_TOT / 128, H_ / 128), 256, 0, stream>>>(y, W2T, (float*)d_out);
}

// Round 8
// 282.361 us; speedup vs baseline: 1.1204x; 1.0547x over previous
//
#include <hip/hip_runtime.h>
#include <cstdint>
#include <cstddef>

#define M_TOT 32768   // B*N
#define D_    256
#define DN_   128
#define TWO_D 512
#define H_    1024
#define TWO_H 2048

typedef unsigned short ushort_t;
typedef __attribute__((ext_vector_type(8))) short bf16x8;  // 8 bf16 = 4 VGPRs
typedef __attribute__((ext_vector_type(4))) float f32x4;

__device__ __forceinline__ ushort_t f2bf(float f) {
  union { float f; uint32_t i; } v; v.f = f;
  uint32_t r = v.i + 0x7fffu + ((v.i >> 16) & 1u);
  return (ushort_t)(r >> 16);
}

__device__ __forceinline__ void async_ld16(const void* g, void* l) {
  __builtin_amdgcn_global_load_lds(
      (const __attribute__((address_space(1))) void*)g,
      (__attribute__((address_space(3))) void*)l, 16, 0, 0);
}

// ---------------- fused prep: cond_ss + transpose(w_in) + transpose(w_out) + gather
// Sections by blockIdx.x: [0,16) cond, [16,144) w_in T, [144,208) w_out T, [208,336) gather.
__device__ __forceinline__ void transpose_body(
    const float* __restrict__ in, ushort_t* __restrict__ out, int R, int C,
    int bb, int tid, float* T) {
  int ctiles = C >> 6;
  int bi = bb / ctiles, bj = bb % ctiles;
  int r0 = bi * 64, c0 = bj * 64;
#pragma unroll
  for (int it = 0; it < 16; ++it) {
    int idx = it * 256 + tid;            // 0..4095
    int r = idx >> 6, c = idx & 63;
    T[r * 65 + c] = in[(size_t)(r0 + r) * C + c0 + c];
  }
  __syncthreads();
#pragma unroll
  for (int it = 0; it < 8; ++it) {
    int idx = it * 256 + tid;            // 0..2047
    int a = idx >> 5;                    // in-col -> out row
    int b = (idx & 31) * 2;              // in-row pair -> out col pair
    uint32_t pk = (uint32_t)f2bf(T[b * 65 + a]) |
                  ((uint32_t)f2bf(T[(b + 1) * 65 + a]) << 16);
    *(uint32_t*)&out[(size_t)(c0 + a) * R + r0 + b] = pk;
  }
}

__global__ __launch_bounds__(256) void prep_kernel(
    const float* __restrict__ ctx, const float* __restrict__ cond_w,
    const float* __restrict__ cond_b, float* __restrict__ ss,
    const float* __restrict__ w_in, ushort_t* __restrict__ WinT,
    const float* __restrict__ w_out, ushort_t* __restrict__ WoutT,
    const float* __restrict__ emb, const int* __restrict__ idx,
    ushort_t* __restrict__ W2T) {
  __shared__ float T[64 * 65];
  int bid = blockIdx.x, tid = threadIdx.x;
  if (bid < 16) {
    // cond_ss: ss[b][j] = ctx[b]·cond_w[:,j] + cond_b[j]
    int j = bid * 256 + tid;             // b = j>>9, col = j&511
    int b = j >> 9, col = j & 511;
    float acc = cond_b[col];
    for (int k = 0; k < DN_; ++k)
      acc += ctx[b * DN_ + k] * cond_w[k * TWO_D + col];
    ss[j] = acc;
  } else if (bid < 144) {
    transpose_body(w_in, WinT, D_, TWO_H, bid - 16, tid, T);
  } else if (bid < 208) {
    transpose_body(w_out, WoutT, H_, D_, bid - 144, tid, T);
  } else {
    // gather: W2T[f*8+o][d] = emb[idx[f]][d*8+o]
    int f = bid - 208;                   // 0..127
    bool looks64 = (idx[1] == 0) & (idx[3] == 0) & (idx[5] == 0) & (idx[7] == 0);
    int fi = looks64 ? idx[2 * f] : idx[f];
    const float* src = emb + (size_t)fi * 2048;
    int o = tid >> 5, d0 = (tid & 31) * 8;
    ushort_t buf[8];
#pragma unroll
    for (int k = 0; k < 8; ++k) buf[k] = f2bf(src[(d0 + k) * 8 + o]);
    *(bf16x8*)&W2T[(size_t)(f * 8 + o) * 256 + d0] = *(bf16x8*)buf;
  }
}

// ---------------- fused LayerNorm + FiLM  (one wave per row of 256), f32 in -> bf16 out
__global__ __launch_bounds__(256) void ln_film_kernel(
    const float* __restrict__ x, const float* __restrict__ ss,
    ushort_t* __restrict__ h) {
  int row = blockIdx.x * 4 + (threadIdx.x >> 6);
  int lane = threadIdx.x & 63;
  int b = row >> 12;
  const float* xr = x + (size_t)row * D_;
  float4 pk = *(const float4*)(xr + lane * 4);
  float f0 = pk.x, f1 = pk.y, f2 = pk.z, f3 = pk.w;
  float s = f0 + f1 + f2 + f3;
  float q = f0 * f0 + f1 * f1 + f2 * f2 + f3 * f3;
#pragma unroll
  for (int off = 32; off > 0; off >>= 1) {
    s += __shfl_xor(s, off, 64);
    q += __shfl_xor(q, off, 64);
  }
  float mean = s * (1.0f / 256.0f);
  float var = q * (1.0f / 256.0f) - mean * mean;
  float rs = rsqrtf(var + 1e-5f);
  int d = lane * 4;
  const float* ssb = ss + b * TWO_D;
  float o0 = (f0 - mean) * rs * (1.0f + ssb[d + 0]) + ssb[256 + d + 0];
  float o1 = (f1 - mean) * rs * (1.0f + ssb[d + 1]) + ssb[256 + d + 1];
  float o2 = (f2 - mean) * rs * (1.0f + ssb[d + 2]) + ssb[256 + d + 2];
  float o3 = (f3 - mean) * rs * (1.0f + ssb[d + 3]) + ssb[256 + d + 3];
  uint2 st;
  st.x = (uint32_t)f2bf(o0) | ((uint32_t)f2bf(o1) << 16);
  st.y = (uint32_t)f2bf(o2) | ((uint32_t)f2bf(o3) << 16);
  *(uint2*)(h + (size_t)row * D_ + lane * 4) = st;
}

// ---------------- fused gated-FFN: y = (gelu(h@Wu+bu)*(h@Wv+bv)) @ Wout + bout
// (proven R4 structure: 128-row blocks, 512 threads, 8 waves 4x2 grid, 32-row
// reg-resident A, 2 MFMAs per B-frag read, swizzled tiles, 6-phase ring,
// counted vmcnt(2) entries — 86.7 µs, no spill)
__global__ __launch_bounds__(512, 2) void ffn_fused_kernel(
    const ushort_t* __restrict__ h,      // [32768][256] bf16
    const ushort_t* __restrict__ WinT,   // [2048][256] bf16 (u rows 0..1023, v 1024..2047)
    const float* __restrict__ bin,       // [2048] f32
    const ushort_t* __restrict__ WoutT,  // [256][1024] bf16
    const float* __restrict__ bout,      // [256] f32
    ushort_t* __restrict__ y) {          // [32768][256] bf16
  __shared__ ushort_t S3[3][8192];       // 3 x 16 KB staging ring
  __shared__ ushort_t Gs[128 * 72];      // 18.4 KB: g chunk, row-major stride 72
  __shared__ float Lbin[2048];           // 8 KB: bin biases
  const int tid = threadIdx.x, lane = tid & 63, wave = tid >> 6;  // wave 0..7
  const int wm = wave >> 1, wn = wave & 1;       // wm 0..3 row-quads
  const int r = lane >> 2, q = lane & 3;         // staging lane decomposition
  const int qs = q ^ ((r >> 1) & 3);             // swizzled source col-chunk
  const int l15 = lane & 15, l4 = lane >> 4;
  const int m0 = blockIdx.x * 128;
  // swizzled fragment offset inside a 16x32 tile (ushort units)
  const int fragoff = l15 * 32 + (l4 ^ ((l15 >> 1) & 3)) * 8;

  // per-thread staging bases (bytes)
  const char* winb  = (const char*)WinT  + r * 512 + qs * 16;
  const char* woutb = (const char*)WoutT + r * 2048 + qs * 16;

  // A fragments: this wave's 32 h-rows, all K=256, in registers (64 VGPR)
  const ushort_t* hp = h + (size_t)(m0 + wm * 32 + l15) * 256 + l4 * 8;
  bf16x8 a_reg[2][8];
#pragma unroll
  for (int rt = 0; rt < 2; ++rt)
#pragma unroll
    for (int kc = 0; kc < 8; ++kc)
      a_reg[rt][kc] = *(const bf16x8*)(hp + rt * 4096 + kc * 32);

  // bin -> LDS (one DMA per wave, pure-DMA keeps vmcnt counts exact)
  async_ld16((const char*)bin + wave * 1024 + lane * 16,
             (char*)Lbin + wave * 1024);

  auto stage_in = [&](ushort_t* dst, int jrow, int k0e) {
#pragma unroll
    for (int i = 0; i < 2; ++i) {
      int tt = i * 8 + wave;             // 0..15; <8 = u, >=8 = v
      int vv = tt >> 3, t7 = tt & 7;
      int ks = t7 >> 2, cc = t7 & 3;     // K-32 sub, gate-col-16 group
      async_ld16(winb + (size_t)vv * 524288 + jrow * 32768 + cc * 8192 +
                     k0e * 2 + ks * 64,
                 &dst[tt * 512]);
    }
  };
  auto stage_wout = [&](ushort_t* dst, int jrow, int s2) {
#pragma unroll
    for (int i = 0; i < 2; ++i) {
      int tt = i * 8 + wave;             // out-col tile nt
      async_ld16(woutb + (size_t)tt * 32768 + jrow * 128 + s2 * 64,
                 &dst[tt * 512]);
    }
  };

  // prologue: first two in-proj quarters of chunk 0
  stage_in(S3[0], 0, 0);
  stage_in(S3[1], 0, 64);

  f32x4 yac[2][8] = {};                  // rows rt*16, out-cols wn*128 + nt8*16

#define ENTRY2()                                        \
  asm volatile("s_waitcnt vmcnt(2)" ::: "memory");      \
  __builtin_amdgcn_s_barrier();                         \
  asm volatile("" ::: "memory");
#define ENTRY2L()                                                  \
  asm volatile("s_waitcnt vmcnt(2) lgkmcnt(0)" ::: "memory");      \
  __builtin_amdgcn_s_barrier();                                    \
  asm volatile("" ::: "memory");

#define MFMA_IN(buf, p_)                                                      \
  {                                                                           \
    const ushort_t* cur_ = (buf);                                             \
    __builtin_amdgcn_s_setprio(1);                                            \
    _Pragma("unroll")                                                         \
    for (int ks = 0; ks < 2; ++ks) {                                          \
      _Pragma("unroll")                                                       \
      for (int jj = 0; jj < 2; ++jj) {                                        \
        int tt = ks * 4 + wn * 2 + jj;                                        \
        bf16x8 bu = *(const bf16x8*)&cur_[tt * 512 + fragoff];                \
        bf16x8 bv = *(const bf16x8*)&cur_[(8 + tt) * 512 + fragoff];          \
        uac[0][jj] = __builtin_amdgcn_mfma_f32_16x16x32_bf16(a_reg[0][(p_)*2+ks], bu, uac[0][jj], 0, 0, 0); \
        uac[1][jj] = __builtin_amdgcn_mfma_f32_16x16x32_bf16(a_reg[1][(p_)*2+ks], bu, uac[1][jj], 0, 0, 0); \
        vac[0][jj] = __builtin_amdgcn_mfma_f32_16x16x32_bf16(a_reg[0][(p_)*2+ks], bv, vac[0][jj], 0, 0, 0); \
        vac[1][jj] = __builtin_amdgcn_mfma_f32_16x16x32_bf16(a_reg[1][(p_)*2+ks], bv, vac[1][jj], 0, 0, 0); \
      }                                                                       \
    }                                                                         \
    __builtin_amdgcn_s_setprio(0);                                            \
  }

#define MFMA_OUT(buf, s2_)                                                    \
  {                                                                           \
    const ushort_t* cur_ = (buf);                                             \
    bf16x8 gf0 = *(const bf16x8*)&Gs[(wm * 32 + l15) * 72 + (s2_) * 32 + l4 * 8];      \
    bf16x8 gf1 = *(const bf16x8*)&Gs[(wm * 32 + 16 + l15) * 72 + (s2_) * 32 + l4 * 8]; \
    __builtin_amdgcn_s_setprio(1);                                            \
    _Pragma("unroll")                                                         \
    for (int nt8 = 0; nt8 < 8; ++nt8) {                                       \
      bf16x8 bw = *(const bf16x8*)&cur_[(wn * 8 + nt8) * 512 + fragoff];      \
      yac[0][nt8] = __builtin_amdgcn_mfma_f32_16x16x32_bf16(gf0, bw, yac[0][nt8], 0, 0, 0); \
      yac[1][nt8] = __builtin_amdgcn_mfma_f32_16x16x32_bf16(gf1, bw, yac[1][nt8], 0, 0, 0); \
    }                                                                         \
    __builtin_amdgcn_s_setprio(0);                                            \
  }

  for (int j = 0; j < 16; ++j) {
    const int jn = (j + 1) & 15;         // wrap keeps vmcnt counts uniform
    f32x4 uac[2][2] = {}, vac[2][2] = {};

    ENTRY2(); stage_in(S3[2], j, 128);  MFMA_IN(S3[0], 0);   // p0
    ENTRY2(); stage_in(S3[0], j, 192);  MFMA_IN(S3[1], 1);   // p1
    ENTRY2(); stage_wout(S3[1], j, 0);  MFMA_IN(S3[2], 2);   // p2
    ENTRY2(); stage_wout(S3[2], j, 1);  MFMA_IN(S3[0], 3);   // p3

    // gelu-gate -> Gs (this wave's 32 rows x 32 gate-cols); flushed at p4 entry
#pragma unroll
    for (int jj = 0; jj < 2; ++jj) {
      int gcol = wn * 32 + jj * 16 + l15;
      float bub = Lbin[j * 64 + gcol];
      float bvb = Lbin[1024 + j * 64 + gcol];
#pragma unroll
      for (int rt = 0; rt < 2; ++rt) {
#pragma unroll
        for (int rr = 0; rr < 4; ++rr) {
          float u = uac[rt][jj][rr] + bub;
          float v = vac[rt][jj][rr] + bvb;
          float t = 0.7978845608028654f * (u + 0.044715f * u * u * u);
          float e = __expf(2.0f * t);
          float th = 1.0f - 2.0f / (e + 1.0f);
          float gl = 0.5f * u * (1.0f + th);
          Gs[(wm * 32 + rt * 16 + l4 * 4 + rr) * 72 + gcol] = f2bf(gl * v);
        }
      }
    }

    ENTRY2L(); stage_in(S3[0], jn, 0);  MFMA_OUT(S3[1], 0);  // p4
    ENTRY2();  stage_in(S3[1], jn, 64); MFMA_OUT(S3[2], 1);  // p5
  }

  // epilogue: y + bout -> bf16 via E (stride 264), two 64-row halves
  asm volatile("s_waitcnt vmcnt(0)" ::: "memory");
  __builtin_amdgcn_s_barrier();
  asm volatile("" ::: "memory");
  ushort_t* E = &S3[0][0];               // 64 x 264 x 2B = 33.8 KB (spans ring)
#pragma unroll
  for (int hh = 0; hh < 2; ++hh) {
    if ((wm >> 1) == hh) {
      int er0 = (wm & 1) * 32;
#pragma unroll
      for (int nt8 = 0; nt8 < 8; ++nt8) {
        int col = wn * 128 + nt8 * 16 + l15;
        float bb = bout[col];
#pragma unroll
        for (int rt = 0; rt < 2; ++rt)
#pragma unroll
          for (int rr = 0; rr < 4; ++rr)
            E[(er0 + rt * 16 + l4 * 4 + rr) * 264 + col] = f2bf(yac[rt][nt8][rr] + bb);
      }
    }
    asm volatile("s_waitcnt lgkmcnt(0)" ::: "memory");
    __builtin_amdgcn_s_barrier();
    asm volatile("" ::: "memory");
#pragma unroll
    for (int it = 0; it < 4; ++it) {
      int id = it * 512 + tid;           // 0..2047: rr = row, cc = 8-col chunk
      int rr = id >> 5, cc = id & 31;
      bf16x8 vv = *(const bf16x8*)&E[rr * 264 + cc * 8];
      *(bf16x8*)&y[(size_t)(m0 + hh * 64 + rr) * 256 + cc * 8] = vv;
    }
    if (hh == 0) {
      __builtin_amdgcn_s_barrier();      // readers done before E is rewritten
      asm volatile("" ::: "memory");
    }
  }
#undef ENTRY2
#undef ENTRY2L
#undef MFMA_IN
#undef MFMA_OUT
}

// ---------------- out GEMM: out[M][1024] = y[M][256] @ W2T[1024][256]^T, f32 out
// 128x128 tile, BK=64, ping-pong 2x32KB staging with counted vmcnt(8),
// swizzled tiles, Cs-roundtrip coalesced float4 epilogue (Cs aliases SB).
__global__ __launch_bounds__(256, 2) void gemm_out_kernel(
    const ushort_t* __restrict__ A, const ushort_t* __restrict__ BT,
    float* __restrict__ C) {
  __shared__ ushort_t SB[2][16384];      // per buf: A tiles 0..15, B tiles 16..31
  const int tid = threadIdx.x, lane = tid & 63, wave = tid >> 6;
  const int wm = wave >> 1, wn = wave & 1;
  const int m0 = blockIdx.x * 128, n0 = blockIdx.y * 128;
  const int r = lane >> 2, q = lane & 3;
  const int qs = q ^ ((r >> 1) & 3);     // swizzled source col-chunk
  const int l15 = lane & 15, l4 = lane >> 4;
  const int fragoff = l15 * 32 + (l4 ^ ((l15 >> 1) & 3)) * 8;
  const int N = 1024, K = 256;

  auto stage = [&](ushort_t* dst, int k0) {
#pragma unroll
    for (int i = 0; i < 4; ++i) {
      int t = i * 4 + wave;              // 0..15
      int rt = t >> 1, ks = t & 1;
      async_ld16(A + (size_t)(m0 + rt * 16 + r) * K + k0 + ks * 32 + qs * 8, &dst[t * 512]);
      async_ld16(BT + (size_t)(n0 + rt * 16 + r) * K + k0 + ks * 32 + qs * 8, &dst[(16 + t) * 512]);
    }
  };

  f32x4 acc[4][4] = {};
  stage(SB[0], 0);                       // 8 DMA/wave
#pragma unroll
  for (int ki = 0; ki < 4; ++ki) {
    __builtin_amdgcn_s_barrier();        // prev buffer's readers done
    asm volatile("" ::: "memory");
    if (ki < 3) {
      stage(SB[(ki + 1) & 1], (ki + 1) * 64);
      asm volatile("s_waitcnt vmcnt(8)" ::: "memory");   // cur landed, next in flight
    } else {
      asm volatile("s_waitcnt vmcnt(0)" ::: "memory");   // last group (issued 1 iter ago)
    }
    __builtin_amdgcn_s_barrier();
    asm volatile("" ::: "memory");
    const ushort_t* cur = SB[ki & 1];
    __builtin_amdgcn_s_setprio(1);
#pragma unroll
    for (int ks = 0; ks < 2; ++ks) {
      bf16x8 a[4], b[4];
#pragma unroll
      for (int i = 0; i < 4; ++i)
        a[i] = *(const bf16x8*)&cur[((wm * 4 + i) * 2 + ks) * 512 + fragoff];
#pragma unroll
      for (int jt = 0; jt < 4; ++jt)
        b[jt] = *(const bf16x8*)&cur[(16 + (wn * 4 + jt) * 2 + ks) * 512 + fragoff];
#pragma unroll
      for (int i = 0; i < 4; ++i)
#pragma unroll
        for (int jt = 0; jt < 4; ++jt)
          acc[i][jt] = __builtin_amdgcn_mfma_f32_16x16x32_bf16(a[i], b[jt], acc[i][jt], 0, 0, 0);
    }
    __builtin_amdgcn_s_setprio(0);
  }
  // coalesced epilogue via Cs (aliases SB; all staging drained above)
  float* Cs = (float*)&SB[0][0];         // 64 x 132 f32 = 33.8 KB
#pragma unroll
  for (int p = 0; p < 2; ++p) {
    __builtin_amdgcn_s_barrier();
    asm volatile("" ::: "memory");
    if (wm == p) {
#pragma unroll
      for (int jt = 0; jt < 4; ++jt) {
        int col = wn * 64 + jt * 16 + l15;
#pragma unroll
        for (int i = 0; i < 4; ++i) {
          int rl = i * 16 + (l4 << 2);
#pragma unroll
          for (int rr = 0; rr < 4; ++rr)
            Cs[(rl + rr) * 132 + col] = acc[i][jt][rr];
        }
      }
    }
    asm volatile("s_waitcnt lgkmcnt(0)" ::: "memory");
    __builtin_amdgcn_s_barrier();
    asm volatile("" ::: "memory");
#pragma unroll
    for (int it = 0; it < 8; ++it) {
      int t = it * 256 + tid;            // 0..2047
      int rr = t >> 5, c = (t & 31) * 4; // row 0..63, col 0..124
      float4 v = *(const float4*)&Cs[rr * 132 + c];
      *(float4*)&C[(size_t)(m0 + p * 64 + rr) * N + n0 + c] = v;
    }
  }
}

extern "C" void kernel_launch(void* const* d_in, const int* in_sizes, int n_in,
                              void* d_out, int out_size, void* d_ws, size_t ws_size,
                              hipStream_t stream) {
  const float* x      = (const float*)d_in[0];
  const float* ctx    = (const float*)d_in[1];
  const int*   idx    = (const int*)d_in[2];
  const float* cond_w = (const float*)d_in[3];
  const float* cond_b = (const float*)d_in[4];
  const float* w_in   = (const float*)d_in[5];
  const float* b_in   = (const float*)d_in[6];
  const float* w_out  = (const float*)d_in[7];
  const float* b_out  = (const float*)d_in[8];
  const float* emb    = (const float*)d_in[9];

  char* w = (char*)d_ws;
  float* ss = (float*)w;           w += (size_t)8 * TWO_D * 4;        // 16 KB
  ushort_t* h = (ushort_t*)w;      w += (size_t)M_TOT * D_ * 2;       // 16.8 MB
  ushort_t* y = (ushort_t*)w;      w += (size_t)M_TOT * D_ * 2;       // 16.8 MB
  ushort_t* WinT = (ushort_t*)w;   w += (size_t)TWO_H * D_ * 2;       // 1 MB
  ushort_t* WoutT = (ushort_t*)w;  w += (size_t)D_ * H_ * 2;          // 0.5 MB
  ushort_t* W2T = (ushort_t*)w;    w += (size_t)H_ * D_ * 2;          // 0.5 MB

  prep_kernel<<<336, 256, 0, stream>>>(ctx, cond_w, cond_b, ss,
                                       w_in, WinT, w_out, WoutT, emb, idx, W2T);
  ln_film_kernel<<<M_TOT / 4, 256, 0, stream>>>(x, ss, h);
  ffn_fused_kernel<<<M_TOT / 128, 512, 0, stream>>>(h, WinT, b_in, WoutT, b_out, y);
  gemm_out_kernel<<<dim3(M_TOT / 128, H_ / 128), 256, 0, stream>>>(y, W2T, (float*)d_out);
}